// Round 9
// baseline (74.614 us; speedup 1.0000x reference)
//
#include <hip/hip_runtime.h>
#include <stdint.h>

// ---------- types & helpers ----------
typedef __attribute__((ext_vector_type(8))) short bf16x8;   // 8 bf16 (4 VGPRs)
typedef __attribute__((ext_vector_type(4))) float f32x4;    // MFMA accum
typedef _Float16 h2 __attribute__((ext_vector_type(2)));    // packed half2

#define AS1 __attribute__((address_space(1)))
#define AS3 __attribute__((address_space(3)))

__device__ __forceinline__ void gload_lds16(const void* g, void* l){
  __builtin_amdgcn_global_load_lds((AS1 void*)g, (AS3 void*)l, 16, 0, 0);
}

__device__ __forceinline__ unsigned short to_bf16(float f){
  union { float f; unsigned int i; } x; x.f = f;
  unsigned int u = x.i;
  unsigned int r = (u + 0x7fffu + ((u >> 16) & 1u)) >> 16;   // RNE
  return (unsigned short)r;
}
__device__ __forceinline__ unsigned short to_f16(float f){
  _Float16 h = (_Float16)f;                                  // v_cvt_f16_f32 (RNE)
  return __builtin_bit_cast(unsigned short, h);
}
__device__ __forceinline__ float bf2f(unsigned short s){
  union { unsigned int i; float f; } x; x.i = ((unsigned int)s) << 16; return x.f;
}

union HU { uint4 u; h2 h[4]; };                              // 16B = 8 f16

// free 4-lane butterfly sum via DPP quad_perm (no LDS pipe)
__device__ __forceinline__ float dpp_qsum(float v){
  int a  = __builtin_bit_cast(int, v);
  int p1 = __builtin_amdgcn_update_dpp(0, a, 0xB1, 0xF, 0xF, true);   // [1,0,3,2] xor1
  float s = v + __builtin_bit_cast(float, p1);
  int c  = __builtin_bit_cast(int, s);
  int p2 = __builtin_amdgcn_update_dpp(0, c, 0x4E, 0xF, 0xF, true);   // [2,3,0,1] xor2
  return s + __builtin_bit_cast(float, p2);
}

// 8-channel f16 dot with f32 accumulate
__device__ __forceinline__ float dot8(const h2* q, const h2* k, float acc){
#if __has_builtin(__builtin_amdgcn_fdot2)
  #pragma unroll
  for (int g = 0; g < 4; g++) acc = __builtin_amdgcn_fdot2(q[g], k[g], acc, false);
#else
  #pragma unroll
  for (int g = 0; g < 4; g++)
    acc += (float)q[g][0] * (float)k[g][0] + (float)q[g][1] * (float)k[g][1];
#endif
  return acc;
}

// ---------- K0: prep = transpose+cast x  AND  cast weights (merged) ----------
__global__ __launch_bounds__(256) void prep_kernel(const float* __restrict__ x,
                                                   unsigned short* __restrict__ xb,
                                                   const float* __restrict__ qkv_w,
                                                   const float* __restrict__ proj_w,
                                                   unsigned short* __restrict__ wq,
                                                   unsigned short* __restrict__ wp){
  int bid = blockIdx.x;
  int tid = threadIdx.x;
  if (bid >= 2048){
    int i = (bid - 2048) * 256 + tid;
    const int nq4 = 768 * 256 / 4;
    const int np4 = 256 * 256 / 4;
    if (i < nq4){
      float4 v = ((const float4*)qkv_w)[i];
      ushort4 u; u.x = to_bf16(v.x); u.y = to_bf16(v.y); u.z = to_bf16(v.z); u.w = to_bf16(v.w);
      ((ushort4*)wq)[i] = u;
    } else if (i < nq4 + np4){
      float4 v = ((const float4*)proj_w)[i - nq4];
      ushort4 u; u.x = to_bf16(v.x); u.y = to_bf16(v.y); u.z = to_bf16(v.z); u.w = to_bf16(v.w);
      ((ushort4*)wp)[i - nq4] = u;
    }
    return;
  }
  __shared__ float tile[64][65];
  int l0 = (bid & 63) * 64;
  int c0 = ((bid >> 6) & 3) * 64;
  int b  = bid >> 8;
  const float* xp = x + ((size_t)b * 256 + c0) * 4096 + l0;
  #pragma unroll
  for (int rep = 0; rep < 4; rep++){
    int idx = rep * 256 + tid;
    int cl = idx >> 4, q4 = idx & 15;
    float4 v = *(const float4*)(xp + (size_t)cl * 4096 + q4 * 4);
    tile[cl][q4 * 4 + 0] = v.x;
    tile[cl][q4 * 4 + 1] = v.y;
    tile[cl][q4 * 4 + 2] = v.z;
    tile[cl][q4 * 4 + 3] = v.w;
  }
  __syncthreads();
  unsigned short* op = xb + ((size_t)b * 4096 + l0) * 256 + c0;
  #pragma unroll
  for (int rep = 0; rep < 4; rep++){
    int idx = rep * 256 + tid;
    int ll = idx >> 4, cp = (idx & 15) * 4;
    ushort4 u;
    u.x = to_bf16(tile[cp + 0][ll]);
    u.y = to_bf16(tile[cp + 1][ll]);
    u.z = to_bf16(tile[cp + 2][ll]);
    u.w = to_bf16(tile[cp + 3][ll]);
    *(ushort4*)(op + (size_t)ll * 256 + cp) = u;
  }
}

// ---------- double-buffered 128x128 GEMM core, BK=64, K=256 ----------
__device__ __forceinline__ void stage_tile(const unsigned short* __restrict__ A,
                                           const unsigned short* __restrict__ B,
                                           unsigned short* la, unsigned short* lb,
                                           int tid, int wave, int k0){
  #pragma unroll
  for (int inst = 0; inst < 4; inst++){
    int u    = inst * 256 + tid;      // 16B unit: row = u>>3 (8 units per 128B row)
    int row  = u >> 3;
    int col  = u & 7;
    int scol = col ^ (row & 7);       // inverse swizzle on the SOURCE
    gload_lds16(A + (size_t)row * 256 + k0 + scol * 8, la + inst * 2048 + wave * 512);
    gload_lds16(B + (size_t)row * 256 + k0 + scol * 8, lb + inst * 2048 + wave * 512);
  }
}

__device__ __forceinline__ void compute_tile(const unsigned short* la, const unsigned short* lb,
                                             int lane, int m_w, int n_w, f32x4 acc[4][4]){
  #pragma unroll
  for (int kk = 0; kk < 2; kk++){
    bf16x8 ar[4], br[4];
    int slot = kk * 4 + (lane >> 4);
    #pragma unroll
    for (int i = 0; i < 4; i++){
      int rowa = m_w + i * 16 + (lane & 15);
      ar[i] = *(const bf16x8*)((const char*)la + rowa * 128 + ((slot ^ (rowa & 7)) << 4));
      int rowb = n_w + i * 16 + (lane & 15);
      br[i] = *(const bf16x8*)((const char*)lb + rowb * 128 + ((slot ^ (rowb & 7)) << 4));
    }
    #pragma unroll
    for (int i = 0; i < 4; i++){
      #pragma unroll
      for (int j = 0; j < 4; j++)
        acc[i][j] = __builtin_amdgcn_mfma_f32_16x16x32_bf16(ar[i], br[j], acc[i][j], 0, 0, 0);
    }
  }
}

// ---------- K1: QKV GEMM -> qkv buffer in F16 ----------
__global__ __launch_bounds__(256, 2) void qkv_gemm_kernel(
    const unsigned short* __restrict__ Wq, const unsigned short* __restrict__ xb,
    const float* __restrict__ qkv_b, unsigned short* __restrict__ qkv){
  __shared__ __align__(16) unsigned short lA[2][128 * 64];   // 2 x 16KB
  __shared__ __align__(16) unsigned short lB[2][128 * 64];
  int orig   = blockIdx.x;
  int b      = orig & 7;           // XCD-pinned batch (L2-resident B-panel)
  int tile   = orig >> 3;
  int tile_m = tile % 6;
  int tile_n = tile / 6;
  int tid  = threadIdx.x;
  int lane = tid & 63;
  int wave = tid >> 6;
  int m_w = (wave >> 1) * 64;
  int n_w = (wave & 1) * 64;

  f32x4 zero; zero[0]=0.f; zero[1]=0.f; zero[2]=0.f; zero[3]=0.f;
  f32x4 acc[4][4];
  #pragma unroll
  for (int i = 0; i < 4; i++)
    #pragma unroll
    for (int j = 0; j < 4; j++) acc[i][j] = zero;

  const unsigned short* Abase = Wq + (size_t)tile_m * 128 * 256;
  const unsigned short* Bbase = xb + ((size_t)b * 4096 + (size_t)tile_n * 128) * 256;

  stage_tile(Abase, Bbase, lA[0], lB[0], tid, wave, 0);
  __syncthreads();
  #pragma unroll
  for (int ks = 0; ks < 4; ks++){
    int cur = ks & 1, nxt = cur ^ 1;
    if (ks < 3) stage_tile(Abase, Bbase, lA[nxt], lB[nxt], tid, wave, (ks + 1) * 64);
    compute_tile(lA[cur], lB[cur], lane, m_w, n_w, acc);
    if (ks < 3) __syncthreads();
  }

  // epilogue: 4 accum rows = 4 consecutive o -> one 8B ushort4 store (f16!)
  #pragma unroll
  for (int i = 0; i < 4; i++){
    #pragma unroll
    for (int j = 0; j < 4; j++){
      int l  = tile_n * 128 + n_w + j * 16 + (lane & 15);
      int o0 = tile_m * 128 + m_w + i * 16 + ((lane >> 4) << 2);
      ushort4 u;
      u.x = to_f16(acc[i][j][0] + qkv_b[o0 + 0]);
      u.y = to_f16(acc[i][j][1] + qkv_b[o0 + 1]);
      u.z = to_f16(acc[i][j][2] + qkv_b[o0 + 2]);
      u.w = to_f16(acc[i][j][3] + qkv_b[o0 + 3]);
      *(ushort4*)(qkv + ((size_t)(b * 24 + (o0 >> 5)) * 4096 + l) * 32 + (o0 & 31)) = u;
    }
  }
}

// ---------- K2: fused attention + fc + residual + LN (branch-free clamped taps) ----------
// Block = 16 pixels x 4 dilations x 4 chan-lanes (256 thr). qkv is F16.
// Tap loads use CLAMPED coordinates and load unconditionally (no exec-mask
// regions -> the 19 loads per head issue back-to-back, true MLP). Zero-pad
// semantics restored afterwards via two selects: sc[p]=in?dot:0 (OOB score
// exactly 0, its exp(0-mx) stays in the denominator) and wp=in?w*inv:0
// (zero V contribution). Identical math to the reference path.
__global__ __launch_bounds__(256, 4) void attn_fcln_kernel(
    const unsigned short* __restrict__ qkv,
    const float* __restrict__ fc_w, const float* __restrict__ fc_b,
    const float* __restrict__ ln_g, const float* __restrict__ ln_b,
    unsigned short* __restrict__ y2){
  __shared__ float fsm[16 * 260];          // [px][260]: 4 pad floats de-alias banks
  int tid  = threadIdx.x;
  int orig = blockIdx.x;
  int b    = orig & 7;                     // XCD-pinned batch
  int l0   = (orig >> 3) * 16;
  int lc   = tid & 3;
  int px   = (tid >> 2) & 15;
  int di   = tid >> 6;                     // wave index = dilation
  int dil  = 1 << di;
  int l    = l0 + px;
  int yy = l >> 6, xx = l & 63;

  // precompute clamped tap indices + validity (no control flow at loads)
  int cidx[9]; bool ib[9];
  #pragma unroll
  for (int p = 0; p < 9; p++){
    int ny = yy + (p / 3 - 1) * dil;
    int nx = xx + (p % 3 - 1) * dil;
    ib[p] = ((unsigned)ny < 64u) && ((unsigned)nx < 64u);
    int nyc = min(max(ny, 0), 63);         // v_med3
    int nxc = min(max(nx, 0), 63);
    cidx[p] = nyc * 64 + nxc;
  }

  #pragma unroll
  for (int head = 0; head < 2; head++){
    const unsigned short* qp = qkv + ((size_t)(b * 24 +      di * 2 + head) * 4096 + l) * 32 + lc * 8;
    const unsigned short* kb = qkv + ((size_t)(b * 24 +  8 + di * 2 + head) * 4096) * 32;
    const unsigned short* vb = qkv + ((size_t)(b * 24 + 16 + di * 2 + head) * 4096) * 32;

    // ---- load phase: Q + 9 K taps + 9 V taps, all unconditional ----
    HU qu; qu.u = *(const uint4*)qp;
    HU ku[9], vu[9];
    #pragma unroll
    for (int p = 0; p < 9; p++)
      ku[p].u = *(const uint4*)(kb + (size_t)cidx[p] * 32 + lc * 8);
    #pragma unroll
    for (int p = 0; p < 9; p++)
      vu[p].u = *(const uint4*)(vb + (size_t)cidx[p] * 32 + lc * 8);

    // ---- compute phase ----
    float sc[9];
    #pragma unroll
    for (int p = 0; p < 9; p++){
      float part = dot8(qu.h, ku[p].h, 0.f);
      float s = dpp_qsum(part) * 0.17677669529663687f;
      sc[p] = ib[p] ? s : 0.f;             // zero-pad: OOB score exactly 0
    }
    float mx = sc[0];
    #pragma unroll
    for (int p = 1; p < 9; p++) mx = fmaxf(mx, sc[p]);
    float w[9]; float den = 0.f;
    #pragma unroll
    for (int p = 0; p < 9; p++){ w[p] = __expf(sc[p] - mx); den += w[p]; }
    float inv = 1.f / den;                 // OOB taps stay in the denominator

    h2 o2[4];
    #pragma unroll
    for (int g = 0; g < 4; g++){ o2[g][0] = (_Float16)0.f; o2[g][1] = (_Float16)0.f; }
    #pragma unroll
    for (int p = 0; p < 9; p++){
      float wpf = ib[p] ? (w[p] * inv) : 0.f;   // zero V contribution for OOB
      _Float16 wh = (_Float16)wpf;
      h2 w2; w2[0] = wh; w2[1] = wh;
      #pragma unroll
      for (int g = 0; g < 4; g++) o2[g] += w2 * vu[p].h[g];   // v_pk_fma_f16
    }
    float* fp = fsm + px * 260 + di * 64 + head * 32 + lc * 8;
    #pragma unroll
    for (int g = 0; g < 4; g++){
      fp[g * 2 + 0] = (float)o2[g][0];
      fp[g * 2 + 1] = (float)o2[g][1];
    }
  }
  __syncthreads();

  // fc + residual + LN: wave w handles pixels w*4..w*4+3; lane = channel c (64)
  int c  = tid & 63;
  int wv = tid >> 6;
  float g  = ln_g[c], bb = ln_b[c];
  float fw[4][4], fb[4];
  #pragma unroll
  for (int t = 0; t < 4; t++){
    fb[t] = fc_b[t];
    #pragma unroll
    for (int s = 0; s < 4; s++) fw[t][s] = fc_w[t * 4 + s];
  }
  #pragma unroll
  for (int pp = 0; pp < 4; pp++){
    int p = wv * 4 + pp;
    float st[4];
    #pragma unroll
    for (int s = 0; s < 4; s++) st[s] = fsm[p * 260 + s * 64 + c];
    unsigned short* op = y2 + ((size_t)(b * 4096) + l0 + p) * 256;
    #pragma unroll
    for (int t = 0; t < 4; t++){
      float v = fb[t] + st[t];
      #pragma unroll
      for (int s = 0; s < 4; s++) v += fw[t][s] * st[s];
      float s1 = v, s2 = v * v;
      #pragma unroll
      for (int m = 1; m < 64; m <<= 1){ s1 += __shfl_xor(s1, m); s2 += __shfl_xor(s2, m); }
      float mu  = s1 * 0.015625f;
      float var = s2 * 0.015625f - mu * mu;
      float rs  = rsqrtf(var + 1e-5f);
      op[t * 64 + c] = to_bf16((v - mu) * rs * g + bb);
    }
  }
}

// ---------- K3: proj GEMM  out[b][o][l] = sum_ch Wp[o][ch]*y2[b][l][ch] + pb ----------
__global__ __launch_bounds__(256, 2) void proj_gemm_kernel(
    const unsigned short* __restrict__ Wp, const unsigned short* __restrict__ y2,
    const float* __restrict__ proj_b, float* __restrict__ out){
  __shared__ __align__(16) unsigned short lA[2][128 * 64];
  __shared__ __align__(16) unsigned short lB[2][128 * 64];
  int orig   = blockIdx.x;
  int b      = orig & 7;           // XCD-pinned batch
  int tile   = orig >> 3;
  int tile_m = tile & 1;
  int tile_n = tile >> 1;
  int tid  = threadIdx.x;
  int lane = tid & 63;
  int wave = tid >> 6;
  int m_w = (wave >> 1) * 64;
  int n_w = (wave & 1) * 64;

  f32x4 zero; zero[0]=0.f; zero[1]=0.f; zero[2]=0.f; zero[3]=0.f;
  f32x4 acc[4][4];
  #pragma unroll
  for (int i = 0; i < 4; i++)
    #pragma unroll
    for (int j = 0; j < 4; j++) acc[i][j] = zero;

  const unsigned short* Abase = Wp + (size_t)tile_m * 128 * 256;
  const unsigned short* Bbase = y2 + ((size_t)b * 4096 + (size_t)tile_n * 128) * 256;

  stage_tile(Abase, Bbase, lA[0], lB[0], tid, wave, 0);
  __syncthreads();
  #pragma unroll
  for (int ks = 0; ks < 4; ks++){
    int cur = ks & 1, nxt = cur ^ 1;
    if (ks < 3) stage_tile(Abase, Bbase, lA[nxt], lB[nxt], tid, wave, (ks + 1) * 64);
    compute_tile(lA[cur], lB[cur], lane, m_w, n_w, acc);
    if (ks < 3) __syncthreads();
  }

  #pragma unroll
  for (int i = 0; i < 4; i++){
    #pragma unroll
    for (int j = 0; j < 4; j++){
      int l = tile_n * 128 + n_w + j * 16 + (lane & 15);
      #pragma unroll
      for (int r = 0; r < 4; r++){
        int o = tile_m * 128 + m_w + i * 16 + ((lane >> 4) << 2) + r;
        out[((size_t)b * 256 + o) * 4096 + l] = acc[i][j][r] + proj_b[o];
      }
    }
  }
}

// ---------- launch ----------
extern "C" void kernel_launch(void* const* d_in, const int* in_sizes, int n_in,
                              void* d_out, int out_size, void* d_ws, size_t ws_size,
                              hipStream_t stream){
  const float* x      = (const float*)d_in[0];
  const float* qkv_w  = (const float*)d_in[1];
  const float* qkv_b  = (const float*)d_in[2];
  const float* fc_w   = (const float*)d_in[3];
  const float* fc_b   = (const float*)d_in[4];
  const float* ln_g   = (const float*)d_in[5];
  const float* ln_b   = (const float*)d_in[6];
  const float* proj_w = (const float*)d_in[7];
  const float* proj_b = (const float*)d_in[8];
  float* out = (float*)d_out;

  // workspace layout (16-bit elements)
  unsigned short* xb  = (unsigned short*)d_ws;            // bf16, 8*4096*256
  unsigned short* qkv = xb  + (size_t)8 * 4096 * 256;     // F16, 8*24*4096*32
  unsigned short* wq  = qkv + (size_t)8 * 24 * 4096 * 32; // bf16 768*256
  unsigned short* wp  = wq  + (size_t)768 * 256;          // bf16 256*256
  unsigned short* y2  = xb;  // alias: xb consumed by qkv_gemm before attn_fcln writes y2

  hipLaunchKernelGGL(prep_kernel,      dim3(2304), dim3(256), 0, stream, x, xb, qkv_w, proj_w, wq, wp);
  hipLaunchKernelGGL(qkv_gemm_kernel,  dim3(1536), dim3(256), 0, stream, wq, xb, qkv_b, qkv);
  hipLaunchKernelGGL(attn_fcln_kernel, dim3(2048), dim3(256), 0, stream, qkv, fc_w, fc_b, ln_g, ln_b, y2);
  hipLaunchKernelGGL(proj_gemm_kernel, dim3(512),  dim3(256), 0, stream, wp, y2, proj_b, out);
}

// Round 10
// 68.144 us; speedup vs baseline: 1.0949x; 1.0949x over previous
//
#include <hip/hip_runtime.h>
#include <stdint.h>

// ---------- types & helpers ----------
typedef __attribute__((ext_vector_type(8))) short bf16x8;   // 8 bf16 (4 VGPRs)
typedef __attribute__((ext_vector_type(4))) float f32x4;    // MFMA accum
typedef _Float16 h2 __attribute__((ext_vector_type(2)));    // packed half2

#define AS1 __attribute__((address_space(1)))
#define AS3 __attribute__((address_space(3)))

__device__ __forceinline__ void gload_lds16(const void* g, void* l){
  __builtin_amdgcn_global_load_lds((AS1 void*)g, (AS3 void*)l, 16, 0, 0);
}

__device__ __forceinline__ unsigned short to_bf16(float f){
  union { float f; unsigned int i; } x; x.f = f;
  unsigned int u = x.i;
  unsigned int r = (u + 0x7fffu + ((u >> 16) & 1u)) >> 16;   // RNE
  return (unsigned short)r;
}
__device__ __forceinline__ unsigned short to_f16(float f){
  _Float16 h = (_Float16)f;                                  // v_cvt_f16_f32 (RNE)
  return __builtin_bit_cast(unsigned short, h);
}
__device__ __forceinline__ float bf2f(unsigned short s){
  union { unsigned int i; float f; } x; x.i = ((unsigned int)s) << 16; return x.f;
}

union HU { uint4 u; h2 h[4]; };                              // 16B = 8 f16

// free 4-lane butterfly sum via DPP quad_perm (no LDS pipe)
__device__ __forceinline__ float dpp_qsum(float v){
  int a  = __builtin_bit_cast(int, v);
  int p1 = __builtin_amdgcn_update_dpp(0, a, 0xB1, 0xF, 0xF, true);   // [1,0,3,2] xor1
  float s = v + __builtin_bit_cast(float, p1);
  int c  = __builtin_bit_cast(int, s);
  int p2 = __builtin_amdgcn_update_dpp(0, c, 0x4E, 0xF, 0xF, true);   // [2,3,0,1] xor2
  return s + __builtin_bit_cast(float, p2);
}

// wave64 sum, pure DPP (no LDS pipe): row_shr 1/2/4/8 -> per-16-row sums in
// lane 15 of each row; row_bcast15 then row_bcast31 accumulate rows; lane 63
// holds the wave total; readlane broadcasts it.
__device__ __forceinline__ float wave_sum64(float v){
  int x;
  x = __builtin_amdgcn_update_dpp(0, __builtin_bit_cast(int, v), 0x111, 0xF, 0xF, true);
  v += __builtin_bit_cast(float, x);                                  // row_shr:1
  x = __builtin_amdgcn_update_dpp(0, __builtin_bit_cast(int, v), 0x112, 0xF, 0xF, true);
  v += __builtin_bit_cast(float, x);                                  // row_shr:2
  x = __builtin_amdgcn_update_dpp(0, __builtin_bit_cast(int, v), 0x114, 0xF, 0xF, true);
  v += __builtin_bit_cast(float, x);                                  // row_shr:4
  x = __builtin_amdgcn_update_dpp(0, __builtin_bit_cast(int, v), 0x118, 0xF, 0xF, true);
  v += __builtin_bit_cast(float, x);                                  // row_shr:8
  x = __builtin_amdgcn_update_dpp(0, __builtin_bit_cast(int, v), 0x142, 0xF, 0xF, true);
  v += __builtin_bit_cast(float, x);                                  // row_bcast:15
  x = __builtin_amdgcn_update_dpp(0, __builtin_bit_cast(int, v), 0x143, 0xF, 0xF, true);
  v += __builtin_bit_cast(float, x);                                  // row_bcast:31
  return __builtin_bit_cast(float, __builtin_amdgcn_readlane(__builtin_bit_cast(int, v), 63));
}

// 8-channel f16 dot with f32 accumulate
__device__ __forceinline__ float dot8(const h2* q, const h2* k, float acc){
#if __has_builtin(__builtin_amdgcn_fdot2)
  #pragma unroll
  for (int g = 0; g < 4; g++) acc = __builtin_amdgcn_fdot2(q[g], k[g], acc, false);
#else
  #pragma unroll
  for (int g = 0; g < 4; g++)
    acc += (float)q[g][0] * (float)k[g][0] + (float)q[g][1] * (float)k[g][1];
#endif
  return acc;
}

// ---------- K0: prep = transpose+cast x  AND  cast weights (merged) ----------
__global__ __launch_bounds__(256) void prep_kernel(const float* __restrict__ x,
                                                   unsigned short* __restrict__ xb,
                                                   const float* __restrict__ qkv_w,
                                                   const float* __restrict__ proj_w,
                                                   unsigned short* __restrict__ wq,
                                                   unsigned short* __restrict__ wp){
  int bid = blockIdx.x;
  int tid = threadIdx.x;
  if (bid >= 2048){
    int i = (bid - 2048) * 256 + tid;
    const int nq4 = 768 * 256 / 4;
    const int np4 = 256 * 256 / 4;
    if (i < nq4){
      float4 v = ((const float4*)qkv_w)[i];
      ushort4 u; u.x = to_bf16(v.x); u.y = to_bf16(v.y); u.z = to_bf16(v.z); u.w = to_bf16(v.w);
      ((ushort4*)wq)[i] = u;
    } else if (i < nq4 + np4){
      float4 v = ((const float4*)proj_w)[i - nq4];
      ushort4 u; u.x = to_bf16(v.x); u.y = to_bf16(v.y); u.z = to_bf16(v.z); u.w = to_bf16(v.w);
      ((ushort4*)wp)[i - nq4] = u;
    }
    return;
  }
  __shared__ float tile[64][65];
  int l0 = (bid & 63) * 64;
  int c0 = ((bid >> 6) & 3) * 64;
  int b  = bid >> 8;
  const float* xp = x + ((size_t)b * 256 + c0) * 4096 + l0;
  #pragma unroll
  for (int rep = 0; rep < 4; rep++){
    int idx = rep * 256 + tid;
    int cl = idx >> 4, q4 = idx & 15;
    float4 v = *(const float4*)(xp + (size_t)cl * 4096 + q4 * 4);
    tile[cl][q4 * 4 + 0] = v.x;
    tile[cl][q4 * 4 + 1] = v.y;
    tile[cl][q4 * 4 + 2] = v.z;
    tile[cl][q4 * 4 + 3] = v.w;
  }
  __syncthreads();
  unsigned short* op = xb + ((size_t)b * 4096 + l0) * 256 + c0;
  #pragma unroll
  for (int rep = 0; rep < 4; rep++){
    int idx = rep * 256 + tid;
    int ll = idx >> 4, cp = (idx & 15) * 4;
    ushort4 u;
    u.x = to_bf16(tile[cp + 0][ll]);
    u.y = to_bf16(tile[cp + 1][ll]);
    u.z = to_bf16(tile[cp + 2][ll]);
    u.w = to_bf16(tile[cp + 3][ll]);
    *(ushort4*)(op + (size_t)ll * 256 + cp) = u;
  }
}

// ---------- double-buffered 128x128 GEMM core, BK=64, K=256 ----------
__device__ __forceinline__ void stage_tile(const unsigned short* __restrict__ A,
                                           const unsigned short* __restrict__ B,
                                           unsigned short* la, unsigned short* lb,
                                           int tid, int wave, int k0){
  #pragma unroll
  for (int inst = 0; inst < 4; inst++){
    int u    = inst * 256 + tid;      // 16B unit: row = u>>3 (8 units per 128B row)
    int row  = u >> 3;
    int col  = u & 7;
    int scol = col ^ (row & 7);       // inverse swizzle on the SOURCE
    gload_lds16(A + (size_t)row * 256 + k0 + scol * 8, la + inst * 2048 + wave * 512);
    gload_lds16(B + (size_t)row * 256 + k0 + scol * 8, lb + inst * 2048 + wave * 512);
  }
}

__device__ __forceinline__ void compute_tile(const unsigned short* la, const unsigned short* lb,
                                             int lane, int m_w, int n_w, f32x4 acc[4][4]){
  #pragma unroll
  for (int kk = 0; kk < 2; kk++){
    bf16x8 ar[4], br[4];
    int slot = kk * 4 + (lane >> 4);
    #pragma unroll
    for (int i = 0; i < 4; i++){
      int rowa = m_w + i * 16 + (lane & 15);
      ar[i] = *(const bf16x8*)((const char*)la + rowa * 128 + ((slot ^ (rowa & 7)) << 4));
      int rowb = n_w + i * 16 + (lane & 15);
      br[i] = *(const bf16x8*)((const char*)lb + rowb * 128 + ((slot ^ (rowb & 7)) << 4));
    }
    #pragma unroll
    for (int i = 0; i < 4; i++){
      #pragma unroll
      for (int j = 0; j < 4; j++)
        acc[i][j] = __builtin_amdgcn_mfma_f32_16x16x32_bf16(ar[i], br[j], acc[i][j], 0, 0, 0);
    }
  }
}

// ---------- K1: QKV GEMM -> qkv buffer in F16 ----------
__global__ __launch_bounds__(256, 2) void qkv_gemm_kernel(
    const unsigned short* __restrict__ Wq, const unsigned short* __restrict__ xb,
    const float* __restrict__ qkv_b, unsigned short* __restrict__ qkv){
  __shared__ __align__(16) unsigned short lA[2][128 * 64];   // 2 x 16KB
  __shared__ __align__(16) unsigned short lB[2][128 * 64];
  int orig   = blockIdx.x;
  int b      = orig & 7;           // XCD-pinned batch (L2-resident B-panel)
  int tile   = orig >> 3;
  int tile_m = tile % 6;
  int tile_n = tile / 6;
  int tid  = threadIdx.x;
  int lane = tid & 63;
  int wave = tid >> 6;
  int m_w = (wave >> 1) * 64;
  int n_w = (wave & 1) * 64;

  f32x4 zero; zero[0]=0.f; zero[1]=0.f; zero[2]=0.f; zero[3]=0.f;
  f32x4 acc[4][4];
  #pragma unroll
  for (int i = 0; i < 4; i++)
    #pragma unroll
    for (int j = 0; j < 4; j++) acc[i][j] = zero;

  const unsigned short* Abase = Wq + (size_t)tile_m * 128 * 256;
  const unsigned short* Bbase = xb + ((size_t)b * 4096 + (size_t)tile_n * 128) * 256;

  stage_tile(Abase, Bbase, lA[0], lB[0], tid, wave, 0);
  __syncthreads();
  #pragma unroll
  for (int ks = 0; ks < 4; ks++){
    int cur = ks & 1, nxt = cur ^ 1;
    if (ks < 3) stage_tile(Abase, Bbase, lA[nxt], lB[nxt], tid, wave, (ks + 1) * 64);
    compute_tile(lA[cur], lB[cur], lane, m_w, n_w, acc);
    if (ks < 3) __syncthreads();
  }

  // epilogue: 4 accum rows = 4 consecutive o -> one 8B ushort4 store (f16!)
  #pragma unroll
  for (int i = 0; i < 4; i++){
    #pragma unroll
    for (int j = 0; j < 4; j++){
      int l  = tile_n * 128 + n_w + j * 16 + (lane & 15);
      int o0 = tile_m * 128 + m_w + i * 16 + ((lane >> 4) << 2);
      ushort4 u;
      u.x = to_f16(acc[i][j][0] + qkv_b[o0 + 0]);
      u.y = to_f16(acc[i][j][1] + qkv_b[o0 + 1]);
      u.z = to_f16(acc[i][j][2] + qkv_b[o0 + 2]);
      u.w = to_f16(acc[i][j][3] + qkv_b[o0 + 3]);
      *(ushort4*)(qkv + ((size_t)(b * 24 + (o0 >> 5)) * 4096 + l) * 32 + (o0 & 31)) = u;
    }
  }
}

// ---------- K2: fused attention + fc + residual + LN (DPP LN reduction) ----------
// Block = 16 pixels x 4 dilations x 4 chan-lanes (256 thr). qkv is F16.
// Attn: branch-free clamped taps (R9). LN: wave64 sums via pure-DPP chain --
// zero LDS-pipe ops (the shfl_xor butterfly was ~192 ds_bpermute/thread).
__global__ __launch_bounds__(256, 4) void attn_fcln_kernel(
    const unsigned short* __restrict__ qkv,
    const float* __restrict__ fc_w, const float* __restrict__ fc_b,
    const float* __restrict__ ln_g, const float* __restrict__ ln_b,
    unsigned short* __restrict__ y2){
  __shared__ float fsm[16 * 260];          // [px][260]: 4 pad floats de-alias banks
  int tid  = threadIdx.x;
  int orig = blockIdx.x;
  int b    = orig & 7;                     // XCD-pinned batch
  int l0   = (orig >> 3) * 16;
  int lc   = tid & 3;
  int px   = (tid >> 2) & 15;
  int di   = tid >> 6;                     // wave index = dilation
  int dil  = 1 << di;
  int l    = l0 + px;
  int yy = l >> 6, xx = l & 63;

  // precompute clamped tap indices + validity (no control flow at loads)
  int cidx[9]; bool ib[9];
  #pragma unroll
  for (int p = 0; p < 9; p++){
    int ny = yy + (p / 3 - 1) * dil;
    int nx = xx + (p % 3 - 1) * dil;
    ib[p] = ((unsigned)ny < 64u) && ((unsigned)nx < 64u);
    int nyc = min(max(ny, 0), 63);         // v_med3
    int nxc = min(max(nx, 0), 63);
    cidx[p] = nyc * 64 + nxc;
  }

  #pragma unroll
  for (int head = 0; head < 2; head++){
    const unsigned short* qp = qkv + ((size_t)(b * 24 +      di * 2 + head) * 4096 + l) * 32 + lc * 8;
    const unsigned short* kb = qkv + ((size_t)(b * 24 +  8 + di * 2 + head) * 4096) * 32;
    const unsigned short* vb = qkv + ((size_t)(b * 24 + 16 + di * 2 + head) * 4096) * 32;

    // ---- load phase: Q + 9 K taps + 9 V taps, all unconditional ----
    HU qu; qu.u = *(const uint4*)qp;
    HU ku[9], vu[9];
    #pragma unroll
    for (int p = 0; p < 9; p++)
      ku[p].u = *(const uint4*)(kb + (size_t)cidx[p] * 32 + lc * 8);
    #pragma unroll
    for (int p = 0; p < 9; p++)
      vu[p].u = *(const uint4*)(vb + (size_t)cidx[p] * 32 + lc * 8);

    // ---- compute phase ----
    float sc[9];
    #pragma unroll
    for (int p = 0; p < 9; p++){
      float part = dot8(qu.h, ku[p].h, 0.f);
      float s = dpp_qsum(part) * 0.17677669529663687f;
      sc[p] = ib[p] ? s : 0.f;             // zero-pad: OOB score exactly 0
    }
    float mx = sc[0];
    #pragma unroll
    for (int p = 1; p < 9; p++) mx = fmaxf(mx, sc[p]);
    float w[9]; float den = 0.f;
    #pragma unroll
    for (int p = 0; p < 9; p++){ w[p] = __expf(sc[p] - mx); den += w[p]; }
    float inv = 1.f / den;                 // OOB taps stay in the denominator

    h2 o2[4];
    #pragma unroll
    for (int g = 0; g < 4; g++){ o2[g][0] = (_Float16)0.f; o2[g][1] = (_Float16)0.f; }
    #pragma unroll
    for (int p = 0; p < 9; p++){
      float wpf = ib[p] ? (w[p] * inv) : 0.f;   // zero V contribution for OOB
      _Float16 wh = (_Float16)wpf;
      h2 w2; w2[0] = wh; w2[1] = wh;
      #pragma unroll
      for (int g = 0; g < 4; g++) o2[g] += w2 * vu[p].h[g];   // v_pk_fma_f16
    }
    float* fp = fsm + px * 260 + di * 64 + head * 32 + lc * 8;
    #pragma unroll
    for (int g = 0; g < 4; g++){
      fp[g * 2 + 0] = (float)o2[g][0];
      fp[g * 2 + 1] = (float)o2[g][1];
    }
  }
  __syncthreads();

  // fc + residual + LN: wave w handles pixels w*4..w*4+3; lane = channel c (64)
  int c  = tid & 63;
  int wv = tid >> 6;
  float g  = ln_g[c], bb = ln_b[c];
  float fw[4][4], fb[4];
  #pragma unroll
  for (int t = 0; t < 4; t++){
    fb[t] = fc_b[t];
    #pragma unroll
    for (int s = 0; s < 4; s++) fw[t][s] = fc_w[t * 4 + s];
  }
  #pragma unroll
  for (int pp = 0; pp < 4; pp++){
    int p = wv * 4 + pp;
    float st[4];
    #pragma unroll
    for (int s = 0; s < 4; s++) st[s] = fsm[p * 260 + s * 64 + c];
    unsigned short* op = y2 + ((size_t)(b * 4096) + l0 + p) * 256;
    #pragma unroll
    for (int t = 0; t < 4; t++){
      float v = fb[t] + st[t];
      #pragma unroll
      for (int s = 0; s < 4; s++) v += fw[t][s] * st[s];
      float s1 = wave_sum64(v);            // pure-DPP wave sum (no LDS pipe)
      float s2 = wave_sum64(v * v);
      float mu  = s1 * 0.015625f;
      float var = s2 * 0.015625f - mu * mu;
      float rs  = rsqrtf(var + 1e-5f);
      op[t * 64 + c] = to_bf16((v - mu) * rs * g + bb);
    }
  }
}

// ---------- K3: proj GEMM  out[b][o][l] = sum_ch Wp[o][ch]*y2[b][l][ch] + pb ----------
__global__ __launch_bounds__(256, 2) void proj_gemm_kernel(
    const unsigned short* __restrict__ Wp, const unsigned short* __restrict__ y2,
    const float* __restrict__ proj_b, float* __restrict__ out){
  __shared__ __align__(16) unsigned short lA[2][128 * 64];
  __shared__ __align__(16) unsigned short lB[2][128 * 64];
  int orig   = blockIdx.x;
  int b      = orig & 7;           // XCD-pinned batch
  int tile   = orig >> 3;
  int tile_m = tile & 1;
  int tile_n = tile >> 1;
  int tid  = threadIdx.x;
  int lane = tid & 63;
  int wave = tid >> 6;
  int m_w = (wave >> 1) * 64;
  int n_w = (wave & 1) * 64;

  f32x4 zero; zero[0]=0.f; zero[1]=0.f; zero[2]=0.f; zero[3]=0.f;
  f32x4 acc[4][4];
  #pragma unroll
  for (int i = 0; i < 4; i++)
    #pragma unroll
    for (int j = 0; j < 4; j++) acc[i][j] = zero;

  const unsigned short* Abase = Wp + (size_t)tile_m * 128 * 256;
  const unsigned short* Bbase = y2 + ((size_t)b * 4096 + (size_t)tile_n * 128) * 256;

  stage_tile(Abase, Bbase, lA[0], lB[0], tid, wave, 0);
  __syncthreads();
  #pragma unroll
  for (int ks = 0; ks < 4; ks++){
    int cur = ks & 1, nxt = cur ^ 1;
    if (ks < 3) stage_tile(Abase, Bbase, lA[nxt], lB[nxt], tid, wave, (ks + 1) * 64);
    compute_tile(lA[cur], lB[cur], lane, m_w, n_w, acc);
    if (ks < 3) __syncthreads();
  }

  #pragma unroll
  for (int i = 0; i < 4; i++){
    #pragma unroll
    for (int j = 0; j < 4; j++){
      int l = tile_n * 128 + n_w + j * 16 + (lane & 15);
      #pragma unroll
      for (int r = 0; r < 4; r++){
        int o = tile_m * 128 + m_w + i * 16 + ((lane >> 4) << 2) + r;
        out[((size_t)b * 256 + o) * 4096 + l] = acc[i][j][r] + proj_b[o];
      }
    }
  }
}

// ---------- launch ----------
extern "C" void kernel_launch(void* const* d_in, const int* in_sizes, int n_in,
                              void* d_out, int out_size, void* d_ws, size_t ws_size,
                              hipStream_t stream){
  const float* x      = (const float*)d_in[0];
  const float* qkv_w  = (const float*)d_in[1];
  const float* qkv_b  = (const float*)d_in[2];
  const float* fc_w   = (const float*)d_in[3];
  const float* fc_b   = (const float*)d_in[4];
  const float* ln_g   = (const float*)d_in[5];
  const float* ln_b   = (const float*)d_in[6];
  const float* proj_w = (const float*)d_in[7];
  const float* proj_b = (const float*)d_in[8];
  float* out = (float*)d_out;

  // workspace layout (16-bit elements)
  unsigned short* xb  = (unsigned short*)d_ws;            // bf16, 8*4096*256
  unsigned short* qkv = xb  + (size_t)8 * 4096 * 256;     // F16, 8*24*4096*32
  unsigned short* wq  = qkv + (size_t)8 * 24 * 4096 * 32; // bf16 768*256
  unsigned short* wp  = wq  + (size_t)768 * 256;          // bf16 256*256
  unsigned short* y2  = xb;  // alias: xb consumed by qkv_gemm before attn_fcln writes y2

  hipLaunchKernelGGL(prep_kernel,      dim3(2304), dim3(256), 0, stream, x, xb, qkv_w, proj_w, wq, wp);
  hipLaunchKernelGGL(qkv_gemm_kernel,  dim3(1536), dim3(256), 0, stream, wq, xb, qkv_b, qkv);
  hipLaunchKernelGGL(attn_fcln_kernel, dim3(2048), dim3(256), 0, stream, qkv, fc_w, fc_b, ln_g, ln_b, y2);
  hipLaunchKernelGGL(proj_gemm_kernel, dim3(512),  dim3(256), 0, stream, wp, y2, proj_b, out);
}